// Round 9
// baseline (287.570 us; speedup 1.0000x reference)
//
#include <hip/hip_runtime.h>
#include <hip/hip_bf16.h>
#include <math.h>

// ---------------------------------------------------------------------------
// MMD-VAE fused pipeline for MI355X (gfx950)
// B=8 S=512 D=1024 DI=4096 DL=64, Nrows = B*S = 4096
// Outputs: recon [4096,1024] f32, latent [4096,64] f32, reg_loss scalar f32
// ---------------------------------------------------------------------------

typedef __attribute__((ext_vector_type(8))) short short8;    // 8 bf16 = 4 VGPR
typedef __attribute__((ext_vector_type(4))) float float4a;   // MFMA accum
typedef __attribute__((ext_vector_type(4))) unsigned short us4;

__device__ inline ushort bf16r(float x) {
    union { float f; unsigned u; } c; c.f = x;
    unsigned r = (c.u + 0x7fffu + ((c.u >> 16) & 1u)) >> 16;
    return (ushort)r;
}

// async global->LDS, 16B per lane, LDS dst = wave-uniform base + lane*16
__device__ inline void gld_lds16(const void* g, void* l) {
    __builtin_amdgcn_global_load_lds(
        (const __attribute__((address_space(1))) void*)g,
        (__attribute__((address_space(3))) void*)l, 16, 0, 0);
}

// tanh-form gelu via sigmoid identity: 0.5v(1+tanh(z)) = v*sigmoid(2z).
// 2z = 1.5957691*v + 0.07135482*v^3.  |err| <~1e-3 (<< bf16 rounding here).
// ~8 VALU ops vs ~20 for the erf-poly version (epilogue was ~45% of GEMM1).
__device__ inline float fast_gelu(float v) {
    float v2 = v * v;
    float u = v * __builtin_fmaf(0.07135481627f, v2, 1.5957691216f);
    u = fminf(u, 30.0f);                       // overflow guard
    float e = __expf(u);
    return v * e * __builtin_amdgcn_rcpf(e + 1.0f);
}

// ---------------- fused pre-pass: conversions + transposes + zeroing -------
__global__ __launch_bounds__(256) void k_pre(
        const float* __restrict__ hidden, ushort* __restrict__ A1bf,
        const float* __restrict__ tsamp, ushort* __restrict__ Tbf,
        float* __restrict__ sq_t, float* __restrict__ acc,
        const float* __restrict__ i0, ushort* __restrict__ o0,
        const float* __restrict__ i1, ushort* __restrict__ o1,
        const float* __restrict__ i2, ushort* __restrict__ o2,
        const float* __restrict__ i3, ushort* __restrict__ o3) {
    int b = blockIdx.x, tid = threadIdx.x;
    if (b == 0 && tid < 24) acc[tid] = 0.0f;   // 3 accumulators, 1 per line
    if (b < 4096) {
        int i = b * 1024 + tid * 4;
        float4 v = *(const float4*)(hidden + i);
        us4 o = {bf16r(v.x), bf16r(v.y), bf16r(v.z), bf16r(v.w)};
        *(us4*)(A1bf + i) = o;
        return;
    }
    if (b < 4352) {
        int i = (b - 4096) * 1024 + tid * 4;
        float4 v = *(const float4*)(tsamp + i);
        us4 o = {bf16r(v.x), bf16r(v.y), bf16r(v.z), bf16r(v.w)};
        *(us4*)(Tbf + i) = o;
        float s = v.x * v.x + v.y * v.y + v.z * v.z + v.w * v.w;
#pragma unroll
        for (int off = 8; off; off >>= 1) s += __shfl_xor(s, off);
        if ((tid & 15) == 0) sq_t[i >> 6] = s;
        return;
    }
    // transpose section
    __shared__ float t[32][33];
    const float* in; ushort* out; int R, C, lb;
    if (b < 8448)      { in = i0; out = o0; R = 1024; C = 4096; lb = b - 4352; }
    else if (b < 8704) { in = i1; out = o1; R = 4096; C = 64;   lb = b - 8448; }
    else if (b < 8960) { in = i2; out = o2; R = 64;   C = 4096; lb = b - 8704; }
    else               { in = i3; out = o3; R = 4096; C = 1024; lb = b - 8960; }
    int bx = (lb % (C / 32)) * 32;
    int by = (lb / (C / 32)) * 32;
    int tx = tid & 31, ty = tid >> 5;   // ty 0..7
#pragma unroll
    for (int i = 0; i < 32; i += 8)
        t[ty + i][tx] = in[(size_t)(by + ty + i) * C + (bx + tx)];
    __syncthreads();
#pragma unroll
    for (int i = 0; i < 32; i += 8)
        out[(size_t)(bx + ty + i) * R + (by + tx)] = bf16r(t[tx][ty + i]);
}

// ---------------- MFMA GEMM: C = epi(A[M,K] @ Bt[N,K]^T + bias) ------------
// BM=128, BK=64, LDK=64, XOR swizzle k8^=row&7 on staging + read (0 bank
// conflicts).  Hoisted staging pointers / LDS offsets.
// BN=128: 2x2 waves of 64x64.  BN=64: 4x1 waves of 32x64.
// EPI 0: +bias, gelu -> bf16 out.   EPI 1: +bias -> f32 out.
// EPI 2: raw fp32 partial (split-K): z==0 -> Out, z>0 -> Out2 if given.
template <int BN, int EPI, bool SWZ>
__global__ __launch_bounds__(256) void k_gemm(
        const ushort* __restrict__ A, const ushort* __restrict__ Bt,
        const float* __restrict__ bias, void* __restrict__ Out,
        float* __restrict__ Out2, int M, int N, int K, int KC) {
    constexpr int BM = 128, BK = 64;
    constexpr int WAVES_N = BN / 64;
    constexpr int WAVES_M = 4 / WAVES_N;
    constexpr int WM = BM / WAVES_M;
    constexpr int MT = WM / 16;
    constexpr int NT = 4;
    constexpr int CA = BM / 32, CB = BN / 32;

    __shared__ ushort sA[BM * 64];
    __shared__ ushort sB[BN * 64];

    const int tid  = threadIdx.x;
    const int wave = tid >> 6, lane = tid & 63;
    const int wm = wave / WAVES_N, wn = wave % WAVES_N;
    int bx = blockIdx.x, by = blockIdx.y;
    if constexpr (SWZ) {
        int lin = blockIdx.x + gridDim.x * blockIdx.y;
        by = lin % gridDim.y;          // n-tile held across 32-block runs
        bx = lin / gridDim.y;
    }
    const int m0 = by * BM, n0 = bx * BN;
    const int lrow = lane & 15, lq = lane >> 4;
    const int srow8 = lane >> 3;
    const int sk8   = lane & 7;
    const int kbeg = blockIdx.z * KC;

    const ushort* pA[CA]; unsigned lA[CA];
#pragma unroll
    for (int j = 0; j < CA; ++j) {
        int c = wave * CA + j;
        int r = c * 8 + srow8;
        pA[j] = &A[(size_t)(m0 + r) * K + kbeg + ((sk8 ^ (r & 7)) * 8)];
        lA[j] = c * 512;
    }
    const ushort* pB[CB]; unsigned lB[CB];
#pragma unroll
    for (int j = 0; j < CB; ++j) {
        int c = wave * CB + j;
        int r = c * 8 + srow8;
        pB[j] = &Bt[(size_t)(n0 + r) * K + kbeg + ((sk8 ^ (r & 7)) * 8)];
        lB[j] = c * 512;
    }
    unsigned aoff[2][MT], boff[2][NT];
#pragma unroll
    for (int h = 0; h < 2; ++h) {
#pragma unroll
        for (int mt = 0; mt < MT; ++mt) {
            int r = wm * WM + mt * 16 + lrow;
            aoff[h][mt] = r * 64 + (((h * 4 + lq) ^ (r & 7)) * 8);
        }
#pragma unroll
        for (int nt = 0; nt < NT; ++nt) {
            int r = wn * 64 + nt * 16 + lrow;
            boff[h][nt] = r * 64 + (((h * 4 + lq) ^ (r & 7)) * 8);
        }
    }

    float4a acc[MT][NT];
#pragma unroll
    for (int mt = 0; mt < MT; ++mt)
#pragma unroll
        for (int nt = 0; nt < NT; ++nt)
            acc[mt][nt] = (float4a){0.f, 0.f, 0.f, 0.f};

    for (int k0 = 0; k0 < KC; k0 += BK) {
#pragma unroll
        for (int j = 0; j < CA; ++j) {
            gld_lds16(pA[j], &sA[lA[j]]);
            pA[j] += BK;
        }
#pragma unroll
        for (int j = 0; j < CB; ++j) {
            gld_lds16(pB[j], &sB[lB[j]]);
            pB[j] += BK;
        }
        __syncthreads();
#pragma unroll
        for (int h = 0; h < 2; ++h) {
            short8 af[MT], bfr[NT];
#pragma unroll
            for (int mt = 0; mt < MT; ++mt)
                af[mt] = *(short8*)(&sA[aoff[h][mt]]);
#pragma unroll
            for (int nt = 0; nt < NT; ++nt)
                bfr[nt] = *(short8*)(&sB[boff[h][nt]]);
#pragma unroll
            for (int mt = 0; mt < MT; ++mt)
#pragma unroll
                for (int nt = 0; nt < NT; ++nt)
                    acc[mt][nt] = __builtin_amdgcn_mfma_f32_16x16x32_bf16(
                        af[mt], bfr[nt], acc[mt][nt], 0, 0, 0);
        }
        __syncthreads();
    }

    float* dstp = nullptr;
    if constexpr (EPI == 2) {
        if (Out2 && blockIdx.z) dstp = Out2;
        else dstp = (float*)Out + (size_t)blockIdx.z * M * N;
    }
#pragma unroll
    for (int mt = 0; mt < MT; ++mt)
#pragma unroll
        for (int nt = 0; nt < NT; ++nt) {
            int col = n0 + wn * 64 + nt * 16 + lrow;
            float bv = 0.f;
            if constexpr (EPI != 2) bv = bias[col];
#pragma unroll
            for (int r = 0; r < 4; ++r) {
                int row = m0 + wm * WM + mt * 16 + lq * 4 + r;
                float v = acc[mt][nt][r] + bv;
                if constexpr (EPI == 0) {
                    ((ushort*)Out)[(size_t)row * N + col] = bf16r(fast_gelu(v));
                } else if constexpr (EPI == 1) {
                    ((float*)Out)[(size_t)row * N + col] = v;
                } else {
                    dstp[(size_t)row * N + col] = v;
                }
            }
        }
}

// ---------------- fused MMD grams (separate-line accumulators) -------------
// blocks 0..527: tt upper-triangle tiles; 528..1055: ll; 1056..2079: tl full.
// Off-diagonal symmetric tiles weighted 2x; diagonal tiles exact (incl i==j).
__global__ __launch_bounds__(256) void k_gram_all(
        const ushort* __restrict__ Tbf, const ushort* __restrict__ Lbf,
        const float* __restrict__ sq_t, const float* __restrict__ sq_l,
        float* __restrict__ accum) {
    __shared__ ushort sX[128 * 64];
    __shared__ ushort sY[128 * 64];
    __shared__ float red[4];

    int id = blockIdx.x;
    int pair, tbx, tby; float w;
    if (id < 1056) {
        pair = (id < 528) ? 0 : 1;
        int t = (pair == 0) ? id : id - 528;
        int r = (int)((sqrtf(8.0f * t + 1.0f) - 1.0f) * 0.5f);
        while ((r + 1) * (r + 2) / 2 <= t) ++r;
        while (r * (r + 1) / 2 > t) --r;
        tby = r; tbx = t - r * (r + 1) / 2;
        w = (tbx == tby) ? 1.0f : 2.0f;
    } else {
        pair = 2; int t = id - 1056;
        tbx = t & 31; tby = t >> 5; w = 1.0f;
    }
    const ushort* Xb = (pair == 1) ? Lbf : Tbf;
    const ushort* Yb = (pair == 0) ? Tbf : Lbf;
    const float* sqX = (pair == 1) ? sq_l : sq_t;
    const float* sqY = (pair == 0) ? sq_t : sq_l;

    const int tid  = threadIdx.x;
    const int wave = tid >> 6, lane = tid & 63;
    const int wm = wave >> 1, wn = wave & 1;
    const int bx = tbx * 128, by = tby * 128;
    const int lrow = lane & 15, lq = lane >> 4;
    const int srow8 = lane >> 3, sk8 = lane & 7;

#pragma unroll
    for (int j = 0; j < 4; ++j) {
        int c = wave * 4 + j;
        int r = c * 8 + srow8;
        int kc = (sk8 ^ (r & 7)) * 8;
        gld_lds16(&Xb[(size_t)(bx + r) * 64 + kc], &sX[c * 512]);
        gld_lds16(&Yb[(size_t)(by + r) * 64 + kc], &sY[c * 512]);
    }

    unsigned xoff[2][4], yoff[2][4];
#pragma unroll
    for (int h = 0; h < 2; ++h)
#pragma unroll
        for (int i = 0; i < 4; ++i) {
            int rx = wm * 64 + i * 16 + lrow;
            int ry = wn * 64 + i * 16 + lrow;
            xoff[h][i] = rx * 64 + (((h * 4 + lq) ^ (rx & 7)) * 8);
            yoff[h][i] = ry * 64 + (((h * 4 + lq) ^ (ry & 7)) * 8);
        }
    __syncthreads();

    float4a acc[4][4];
#pragma unroll
    for (int mt = 0; mt < 4; ++mt)
#pragma unroll
        for (int nt = 0; nt < 4; ++nt)
            acc[mt][nt] = (float4a){0.f, 0.f, 0.f, 0.f};

#pragma unroll
    for (int h = 0; h < 2; ++h) {
        short8 xf[4], yf[4];
#pragma unroll
        for (int mt = 0; mt < 4; ++mt)
            xf[mt] = *(short8*)(&sX[xoff[h][mt]]);
#pragma unroll
        for (int nt = 0; nt < 4; ++nt)
            yf[nt] = *(short8*)(&sY[yoff[h][nt]]);
#pragma unroll
        for (int mt = 0; mt < 4; ++mt)
#pragma unroll
            for (int nt = 0; nt < 4; ++nt)
                acc[mt][nt] = __builtin_amdgcn_mfma_f32_16x16x32_bf16(
                    xf[mt], yf[nt], acc[mt][nt], 0, 0, 0);
    }

    float sy[4];
#pragma unroll
    for (int nt = 0; nt < 4; ++nt)
        sy[nt] = sqY[by + wn * 64 + nt * 16 + lrow];
    float s = 0.f;
#pragma unroll
    for (int mt = 0; mt < 4; ++mt)
#pragma unroll
        for (int r = 0; r < 4; ++r) {
            float sx = sqX[bx + wm * 64 + mt * 16 + lq * 4 + r];
#pragma unroll
            for (int nt = 0; nt < 4; ++nt)
                s += __expf((2.0f * acc[mt][nt][r] - sx - sy[nt]) * (1.0f / 4096.0f));
        }
    s *= w;
#pragma unroll
    for (int off = 32; off; off >>= 1) s += __shfl_xor(s, off);
    if ((tid & 63) == 0) red[tid >> 6] = s;
    __syncthreads();
    if (tid == 0) atomicAdd(accum + pair * 8, red[0] + red[1] + red[2] + red[3]);
}

// ---------------- LayerNorm over 64, split-K reduce, + latent sqnorm -------
__global__ __launch_bounds__(256) void k_ln64_red(
        const float* __restrict__ part, int npart,
        const float* __restrict__ bias, const float* __restrict__ g,
        const float* __restrict__ b, float* __restrict__ outf,
        ushort* __restrict__ outb, float* __restrict__ sq_l) {
    int wave = threadIdx.x >> 6, lane = threadIdx.x & 63;
    int row = blockIdx.x * 4 + wave;
    float x = bias[lane];
    for (int s = 0; s < npart; ++s)
        x += part[(size_t)s * 4096 * 64 + row * 64 + lane];
    float s = x;
#pragma unroll
    for (int off = 32; off; off >>= 1) s += __shfl_xor(s, off);
    float mu = s * (1.0f / 64.0f);
    float d = x - mu;
    float v = d * d;
#pragma unroll
    for (int off = 32; off; off >>= 1) v += __shfl_xor(v, off);
    float rs = rsqrtf(v * (1.0f / 64.0f) + 1e-9f);
    float y = d * rs * g[lane] + b[lane];
    outf[row * 64 + lane] = y;
    outb[row * 64 + lane] = bf16r(y);
    float q = y * y;
#pragma unroll
    for (int off = 32; off; off >>= 1) q += __shfl_xor(q, off);
    if (lane == 0) sq_l[row] = q;
}

// ---------------- LayerNorm over 1024 (single input, bias added here) ------
__global__ __launch_bounds__(256) void k_ln1024(
        const float* __restrict__ h, const float* __restrict__ g,
        const float* __restrict__ b, float* __restrict__ out) {
    __shared__ float red[4];
    int row = blockIdx.x, tid = threadIdx.x;
    const float4 v = *(const float4*)(h + (size_t)row * 1024 + tid * 4);
    float s = v.x + v.y + v.z + v.w;
#pragma unroll
    for (int off = 32; off; off >>= 1) s += __shfl_xor(s, off);
    if ((tid & 63) == 0) red[tid >> 6] = s;
    __syncthreads();
    float mu = (red[0] + red[1] + red[2] + red[3]) * (1.0f / 1024.0f);
    float dx = v.x - mu, dy = v.y - mu, dz = v.z - mu, dw = v.w - mu;
    float q = dx * dx + dy * dy + dz * dz + dw * dw;
#pragma unroll
    for (int off = 32; off; off >>= 1) q += __shfl_xor(q, off);
    __syncthreads();
    if ((tid & 63) == 0) red[tid >> 6] = q;
    __syncthreads();
    float rs = rsqrtf((red[0] + red[1] + red[2] + red[3]) * (1.0f / 1024.0f) + 1e-9f);
    const float4 gv = *(const float4*)(g + tid * 4);
    const float4 bv = *(const float4*)(b + tid * 4);
    float4 o;
    o.x = dx * rs * gv.x + bv.x;
    o.y = dy * rs * gv.y + bv.y;
    o.z = dz * rs * gv.z + bv.z;
    o.w = dw * rs * gv.w + bv.w;
    *(float4*)(out + (size_t)row * 1024 + tid * 4) = o;
}

__global__ void k_finalize(const float* __restrict__ accum, float* __restrict__ out) {
    // km_i = accum_i / 4096^2 ; reg = (km0 + km1 - 2*km2) / B * S = mmd * 64
    out[0] = (accum[0] + accum[8] - 2.0f * accum[16]) * (64.0f / (4096.0f * 4096.0f));
}

// ---------------------------------------------------------------------------
extern "C" void kernel_launch(void* const* d_in, const int* in_sizes, int n_in,
                              void* d_out, int out_size, void* d_ws, size_t ws_size,
                              hipStream_t stream) {
    const float* hidden   = (const float*)d_in[0];
    const float* tsamp    = (const float*)d_in[1];
    const float* enc_w1   = (const float*)d_in[2];
    const float* enc_b1   = (const float*)d_in[3];
    const float* enc_w2   = (const float*)d_in[4];
    const float* enc_b2   = (const float*)d_in[5];
    const float* enc_ln_g = (const float*)d_in[6];
    const float* enc_ln_b = (const float*)d_in[7];
    const float* dec_w1   = (const float*)d_in[8];
    const float* dec_b1   = (const float*)d_in[9];
    const float* dec_w2   = (const float*)d_in[10];
    const float* dec_b2   = (const float*)d_in[11];
    const float* dec_ln_g = (const float*)d_in[12];
    const float* dec_ln_b = (const float*)d_in[13];

    float* out      = (float*)d_out;
    float* recon    = out;                 // 4096*1024
    float* latent_f = out + 4194304;       // 4096*64
    float* reg      = out + 4456448;       // scalar

    char* ws = (char*)d_ws;
    const size_t MB = 1024 * 1024;
    ushort* A1bf = (ushort*)(ws + 0);                 // 8MB  hidden bf16 (dead after GEMM1)
    ushort* W1t  = (ushort*)(ws + 8 * MB);            // 8MB  (dead after GEMM1)
    float*  part = (float*)(ws + 0);                  // 16MB GEMM2 split-K partials [16][4096,64]
    float*  h4   = (float*)(ws + 0);                  // 16MB GEMM4 out (part dead by then)
    ushort* H1bf = (ushort*)(ws + 16 * MB);           // 32MB enc hidden, later dec hidden
    ushort* W4t  = (ushort*)(ws + 48 * MB);           // 8MB  [1024,4096]
    ushort* W2t  = (ushort*)(ws + 56 * MB);           // 512K [64,4096]
    ushort* W3t  = (ushort*)(ws + 56 * MB + 512 * 1024); // 512K [4096,64]
    ushort* Lbf  = (ushort*)(ws + 57 * MB);           // 512K latent bf16
    float*  sq_t = (float*)(ws + 59 * MB);            // 16KB
    float*  sq_l = (float*)(ws + 59 * MB + 16384);    // 16KB
    float*  acc3 = (float*)(ws + 59 * MB + 32768);    // 3 accumulators @ 64B stride
    ushort* Tbf  = (ushort*)(ws + 59 * MB + 65536);   // 512K tsamp bf16

    // pre-pass: all conversions, transposes, tsamp sqnorms, accumulator zeroing
    k_pre<<<13056, 256, 0, stream>>>(hidden, A1bf, tsamp, Tbf, sq_t, acc3,
                                     enc_w1, W1t, enc_w2, W2t,
                                     dec_w1, W3t, dec_w2, W4t);

    // encoder
    k_gemm<64, 0, false><<<dim3(64, 32, 1), 256, 0, stream>>>(
        A1bf, W1t, enc_b1, H1bf, nullptr, 4096, 4096, 1024, 1024);
    // GEMM2 split-K=16: 512 blocks = 2/CU
    k_gemm<64, 2, false><<<dim3(1, 32, 16), 256, 0, stream>>>(
        H1bf, W2t, nullptr, part, nullptr, 4096, 64, 4096, 256);
    k_ln64_red<<<1024, 256, 0, stream>>>(part, 16, enc_b2, enc_ln_g, enc_ln_b,
                                         latent_f, Lbf, sq_l);

    // decoder
    k_gemm<64, 0, false><<<dim3(64, 32, 1), 256, 0, stream>>>(
        Lbf, W3t, dec_b1, H1bf, nullptr, 4096, 4096, 64, 64);
    // GEMM4: no split-K (512 blocks = 2/CU), direct bias+f32 out; saves
    // 16MB partial write + 16MB extra read in LN
    k_gemm<64, 1, true><<<dim3(16, 32, 1), 256, 0, stream>>>(
        H1bf, W4t, dec_b2, h4, nullptr, 4096, 1024, 4096, 4096);
    k_ln1024<<<4096, 256, 0, stream>>>(h4, dec_ln_g, dec_ln_b, recon);

    // MMD: grams (separate-line accumulators), then tiny finalize
    k_gram_all<<<2080, 256, 0, stream>>>(Tbf, Lbf, sq_t, sq_l, acc3);
    k_finalize<<<1, 1, 0, stream>>>(acc3, reg);
}

// Round 10
// 272.631 us; speedup vs baseline: 1.0548x; 1.0548x over previous
//
#include <hip/hip_runtime.h>
#include <hip/hip_bf16.h>
#include <math.h>

// ---------------------------------------------------------------------------
// MMD-VAE fused pipeline for MI355X (gfx950)
// B=8 S=512 D=1024 DI=4096 DL=64, Nrows = B*S = 4096
// Outputs: recon [4096,1024] f32, latent [4096,64] f32, reg_loss scalar f32
// ---------------------------------------------------------------------------

typedef __attribute__((ext_vector_type(8))) short short8;    // 8 bf16 = 4 VGPR
typedef __attribute__((ext_vector_type(4))) float float4a;   // MFMA accum
typedef __attribute__((ext_vector_type(4))) unsigned short us4;

__device__ inline ushort bf16r(float x) {
    union { float f; unsigned u; } c; c.f = x;
    unsigned r = (c.u + 0x7fffu + ((c.u >> 16) & 1u)) >> 16;
    return (ushort)r;
}

// async global->LDS, 16B per lane, LDS dst = wave-uniform base + lane*16
__device__ inline void gld_lds16(const void* g, void* l) {
    __builtin_amdgcn_global_load_lds(
        (const __attribute__((address_space(1))) void*)g,
        (__attribute__((address_space(3))) void*)l, 16, 0, 0);
}

// tanh-form gelu via sigmoid identity: 0.5v(1+tanh(z)) = v*sigmoid(2z).
// 2z = 1.5957691*v + 0.07135482*v^3.  |err| <~1e-3 (<< bf16 rounding here).
__device__ inline float fast_gelu(float v) {
    float v2 = v * v;
    float u = v * __builtin_fmaf(0.07135481627f, v2, 1.5957691216f);
    u = fminf(u, 30.0f);                       // overflow guard
    float e = __expf(u);
    return v * e * __builtin_amdgcn_rcpf(e + 1.0f);
}

// ---------------- fused pre-pass: conversions + transposes + zeroing -------
__global__ __launch_bounds__(256) void k_pre(
        const float* __restrict__ hidden, ushort* __restrict__ A1bf,
        const float* __restrict__ tsamp, ushort* __restrict__ Tbf,
        float* __restrict__ sq_t, float* __restrict__ acc,
        const float* __restrict__ i0, ushort* __restrict__ o0,
        const float* __restrict__ i1, ushort* __restrict__ o1,
        const float* __restrict__ i2, ushort* __restrict__ o2,
        const float* __restrict__ i3, ushort* __restrict__ o3) {
    int b = blockIdx.x, tid = threadIdx.x;
    if (b == 0 && tid < 24) acc[tid] = 0.0f;   // 3 accumulators, 1 per line
    if (b < 4096) {
        int i = b * 1024 + tid * 4;
        float4 v = *(const float4*)(hidden + i);
        us4 o = {bf16r(v.x), bf16r(v.y), bf16r(v.z), bf16r(v.w)};
        *(us4*)(A1bf + i) = o;
        return;
    }
    if (b < 4352) {
        int i = (b - 4096) * 1024 + tid * 4;
        float4 v = *(const float4*)(tsamp + i);
        us4 o = {bf16r(v.x), bf16r(v.y), bf16r(v.z), bf16r(v.w)};
        *(us4*)(Tbf + i) = o;
        float s = v.x * v.x + v.y * v.y + v.z * v.z + v.w * v.w;
#pragma unroll
        for (int off = 8; off; off >>= 1) s += __shfl_xor(s, off);
        if ((tid & 15) == 0) sq_t[i >> 6] = s;
        return;
    }
    // transpose section
    __shared__ float t[32][33];
    const float* in; ushort* out; int R, C, lb;
    if (b < 8448)      { in = i0; out = o0; R = 1024; C = 4096; lb = b - 4352; }
    else if (b < 8704) { in = i1; out = o1; R = 4096; C = 64;   lb = b - 8448; }
    else if (b < 8960) { in = i2; out = o2; R = 64;   C = 4096; lb = b - 8704; }
    else               { in = i3; out = o3; R = 4096; C = 1024; lb = b - 8960; }
    int bx = (lb % (C / 32)) * 32;
    int by = (lb / (C / 32)) * 32;
    int tx = tid & 31, ty = tid >> 5;   // ty 0..7
#pragma unroll
    for (int i = 0; i < 32; i += 8)
        t[ty + i][tx] = in[(size_t)(by + ty + i) * C + (bx + tx)];
    __syncthreads();
#pragma unroll
    for (int i = 0; i < 32; i += 8)
        out[(size_t)(bx + ty + i) * R + (by + tx)] = bf16r(t[tx][ty + i]);
}

// ---------------- MFMA GEMM: C = epi(A[M,K] @ Bt[N,K]^T + bias) ------------
// BM=128, BK=64, LDK=64, XOR swizzle k8^=row&7 on staging + read (0 bank
// conflicts).  Hoisted staging pointers / LDS offsets.
// BN=128: 2x2 waves of 64x64.  BN=64: 4x1 waves of 32x64.
// EPI 0: +bias, gelu -> bf16 out.   EPI 1: +bias -> f32 out.
// EPI 2: raw fp32 partial (split-K): z==0 -> Out, z>0 -> Out2 if given.
template <int BN, int EPI, bool SWZ>
__global__ __launch_bounds__(256) void k_gemm(
        const ushort* __restrict__ A, const ushort* __restrict__ Bt,
        const float* __restrict__ bias, void* __restrict__ Out,
        float* __restrict__ Out2, int M, int N, int K, int KC) {
    constexpr int BM = 128, BK = 64;
    constexpr int WAVES_N = BN / 64;
    constexpr int WAVES_M = 4 / WAVES_N;
    constexpr int WM = BM / WAVES_M;
    constexpr int MT = WM / 16;
    constexpr int NT = 4;
    constexpr int CA = BM / 32, CB = BN / 32;

    __shared__ ushort sA[BM * 64];
    __shared__ ushort sB[BN * 64];

    const int tid  = threadIdx.x;
    const int wave = tid >> 6, lane = tid & 63;
    const int wm = wave / WAVES_N, wn = wave % WAVES_N;
    int bx = blockIdx.x, by = blockIdx.y;
    if constexpr (SWZ) {
        int lin = blockIdx.x + gridDim.x * blockIdx.y;
        by = lin % gridDim.y;          // m-tile fast => same XCD per A-row
        bx = lin / gridDim.y;
    }
    const int m0 = by * BM, n0 = bx * BN;
    const int lrow = lane & 15, lq = lane >> 4;
    const int srow8 = lane >> 3;
    const int sk8   = lane & 7;
    const int kbeg = blockIdx.z * KC;

    const ushort* pA[CA]; unsigned lA[CA];
#pragma unroll
    for (int j = 0; j < CA; ++j) {
        int c = wave * CA + j;
        int r = c * 8 + srow8;
        pA[j] = &A[(size_t)(m0 + r) * K + kbeg + ((sk8 ^ (r & 7)) * 8)];
        lA[j] = c * 512;
    }
    const ushort* pB[CB]; unsigned lB[CB];
#pragma unroll
    for (int j = 0; j < CB; ++j) {
        int c = wave * CB + j;
        int r = c * 8 + srow8;
        pB[j] = &Bt[(size_t)(n0 + r) * K + kbeg + ((sk8 ^ (r & 7)) * 8)];
        lB[j] = c * 512;
    }
    unsigned aoff[2][MT], boff[2][NT];
#pragma unroll
    for (int h = 0; h < 2; ++h) {
#pragma unroll
        for (int mt = 0; mt < MT; ++mt) {
            int r = wm * WM + mt * 16 + lrow;
            aoff[h][mt] = r * 64 + (((h * 4 + lq) ^ (r & 7)) * 8);
        }
#pragma unroll
        for (int nt = 0; nt < NT; ++nt) {
            int r = wn * 64 + nt * 16 + lrow;
            boff[h][nt] = r * 64 + (((h * 4 + lq) ^ (r & 7)) * 8);
        }
    }

    float4a acc[MT][NT];
#pragma unroll
    for (int mt = 0; mt < MT; ++mt)
#pragma unroll
        for (int nt = 0; nt < NT; ++nt)
            acc[mt][nt] = (float4a){0.f, 0.f, 0.f, 0.f};

    for (int k0 = 0; k0 < KC; k0 += BK) {
#pragma unroll
        for (int j = 0; j < CA; ++j) {
            gld_lds16(pA[j], &sA[lA[j]]);
            pA[j] += BK;
        }
#pragma unroll
        for (int j = 0; j < CB; ++j) {
            gld_lds16(pB[j], &sB[lB[j]]);
            pB[j] += BK;
        }
        __syncthreads();
#pragma unroll
        for (int h = 0; h < 2; ++h) {
            short8 af[MT], bfr[NT];
#pragma unroll
            for (int mt = 0; mt < MT; ++mt)
                af[mt] = *(short8*)(&sA[aoff[h][mt]]);
#pragma unroll
            for (int nt = 0; nt < NT; ++nt)
                bfr[nt] = *(short8*)(&sB[boff[h][nt]]);
#pragma unroll
            for (int mt = 0; mt < MT; ++mt)
#pragma unroll
                for (int nt = 0; nt < NT; ++nt)
                    acc[mt][nt] = __builtin_amdgcn_mfma_f32_16x16x32_bf16(
                        af[mt], bfr[nt], acc[mt][nt], 0, 0, 0);
        }
        __syncthreads();
    }

    float* dstp = nullptr;
    if constexpr (EPI == 2) {
        if (Out2 && blockIdx.z) dstp = Out2;
        else dstp = (float*)Out + (size_t)blockIdx.z * M * N;
    }
#pragma unroll
    for (int mt = 0; mt < MT; ++mt)
#pragma unroll
        for (int nt = 0; nt < NT; ++nt) {
            int col = n0 + wn * 64 + nt * 16 + lrow;
            float bv = 0.f;
            if constexpr (EPI != 2) bv = bias[col];
#pragma unroll
            for (int r = 0; r < 4; ++r) {
                int row = m0 + wm * WM + mt * 16 + lq * 4 + r;
                float v = acc[mt][nt][r] + bv;
                if constexpr (EPI == 0) {
                    ((ushort*)Out)[(size_t)row * N + col] = bf16r(fast_gelu(v));
                } else if constexpr (EPI == 1) {
                    ((float*)Out)[(size_t)row * N + col] = v;
                } else {
                    dstp[(size_t)row * N + col] = v;
                }
            }
        }
}

// ---------------- fused MMD grams (separate-line accumulators) -------------
// blocks 0..527: tt upper-triangle tiles; 528..1055: ll; 1056..2079: tl full.
// Off-diagonal symmetric tiles weighted 2x; diagonal tiles exact (incl i==j).
__global__ __launch_bounds__(256) void k_gram_all(
        const ushort* __restrict__ Tbf, const ushort* __restrict__ Lbf,
        const float* __restrict__ sq_t, const float* __restrict__ sq_l,
        float* __restrict__ accum) {
    __shared__ ushort sX[128 * 64];
    __shared__ ushort sY[128 * 64];
    __shared__ float red[4];

    int id = blockIdx.x;
    int pair, tbx, tby; float w;
    if (id < 1056) {
        pair = (id < 528) ? 0 : 1;
        int t = (pair == 0) ? id : id - 528;
        int r = (int)((sqrtf(8.0f * t + 1.0f) - 1.0f) * 0.5f);
        while ((r + 1) * (r + 2) / 2 <= t) ++r;
        while (r * (r + 1) / 2 > t) --r;
        tby = r; tbx = t - r * (r + 1) / 2;
        w = (tbx == tby) ? 1.0f : 2.0f;
    } else {
        pair = 2; int t = id - 1056;
        tbx = t & 31; tby = t >> 5; w = 1.0f;
    }
    const ushort* Xb = (pair == 1) ? Lbf : Tbf;
    const ushort* Yb = (pair == 0) ? Tbf : Lbf;
    const float* sqX = (pair == 1) ? sq_l : sq_t;
    const float* sqY = (pair == 0) ? sq_t : sq_l;

    const int tid  = threadIdx.x;
    const int wave = tid >> 6, lane = tid & 63;
    const int wm = wave >> 1, wn = wave & 1;
    const int bx = tbx * 128, by = tby * 128;
    const int lrow = lane & 15, lq = lane >> 4;
    const int srow8 = lane >> 3, sk8 = lane & 7;

#pragma unroll
    for (int j = 0; j < 4; ++j) {
        int c = wave * 4 + j;
        int r = c * 8 + srow8;
        int kc = (sk8 ^ (r & 7)) * 8;
        gld_lds16(&Xb[(size_t)(bx + r) * 64 + kc], &sX[c * 512]);
        gld_lds16(&Yb[(size_t)(by + r) * 64 + kc], &sY[c * 512]);
    }

    unsigned xoff[2][4], yoff[2][4];
#pragma unroll
    for (int h = 0; h < 2; ++h)
#pragma unroll
        for (int i = 0; i < 4; ++i) {
            int rx = wm * 64 + i * 16 + lrow;
            int ry = wn * 64 + i * 16 + lrow;
            xoff[h][i] = rx * 64 + (((h * 4 + lq) ^ (rx & 7)) * 8);
            yoff[h][i] = ry * 64 + (((h * 4 + lq) ^ (ry & 7)) * 8);
        }
    __syncthreads();

    float4a acc[4][4];
#pragma unroll
    for (int mt = 0; mt < 4; ++mt)
#pragma unroll
        for (int nt = 0; nt < 4; ++nt)
            acc[mt][nt] = (float4a){0.f, 0.f, 0.f, 0.f};

#pragma unroll
    for (int h = 0; h < 2; ++h) {
        short8 xf[4], yf[4];
#pragma unroll
        for (int mt = 0; mt < 4; ++mt)
            xf[mt] = *(short8*)(&sX[xoff[h][mt]]);
#pragma unroll
        for (int nt = 0; nt < 4; ++nt)
            yf[nt] = *(short8*)(&sY[yoff[h][nt]]);
#pragma unroll
        for (int mt = 0; mt < 4; ++mt)
#pragma unroll
            for (int nt = 0; nt < 4; ++nt)
                acc[mt][nt] = __builtin_amdgcn_mfma_f32_16x16x32_bf16(
                    xf[mt], yf[nt], acc[mt][nt], 0, 0, 0);
    }

    float sy[4];
#pragma unroll
    for (int nt = 0; nt < 4; ++nt)
        sy[nt] = sqY[by + wn * 64 + nt * 16 + lrow];
    float s = 0.f;
#pragma unroll
    for (int mt = 0; mt < 4; ++mt)
#pragma unroll
        for (int r = 0; r < 4; ++r) {
            float sx = sqX[bx + wm * 64 + mt * 16 + lq * 4 + r];
#pragma unroll
            for (int nt = 0; nt < 4; ++nt)
                s += __expf((2.0f * acc[mt][nt][r] - sx - sy[nt]) * (1.0f / 4096.0f));
        }
    s *= w;
#pragma unroll
    for (int off = 32; off; off >>= 1) s += __shfl_xor(s, off);
    if ((tid & 63) == 0) red[tid >> 6] = s;
    __syncthreads();
    if (tid == 0) atomicAdd(accum + pair * 8, red[0] + red[1] + red[2] + red[3]);
}

// ---------------- LayerNorm over 64, split-K reduce, + latent sqnorm -------
__global__ __launch_bounds__(256) void k_ln64_red(
        const float* __restrict__ part, int npart,
        const float* __restrict__ bias, const float* __restrict__ g,
        const float* __restrict__ b, float* __restrict__ outf,
        ushort* __restrict__ outb, float* __restrict__ sq_l) {
    int wave = threadIdx.x >> 6, lane = threadIdx.x & 63;
    int row = blockIdx.x * 4 + wave;
    float x = bias[lane];
    for (int s = 0; s < npart; ++s)
        x += part[(size_t)s * 4096 * 64 + row * 64 + lane];
    float s = x;
#pragma unroll
    for (int off = 32; off; off >>= 1) s += __shfl_xor(s, off);
    float mu = s * (1.0f / 64.0f);
    float d = x - mu;
    float v = d * d;
#pragma unroll
    for (int off = 32; off; off >>= 1) v += __shfl_xor(v, off);
    float rs = rsqrtf(v * (1.0f / 64.0f) + 1e-9f);
    float y = d * rs * g[lane] + b[lane];
    outf[row * 64 + lane] = y;
    outb[row * 64 + lane] = bf16r(y);
    float q = y * y;
#pragma unroll
    for (int off = 32; off; off >>= 1) q += __shfl_xor(q, off);
    if (lane == 0) sq_l[row] = q;
}

// ---------------- LayerNorm over 1024 with 2-partial reduce ----------------
// p1 may alias out (read-before-write within the same block/row).
__global__ __launch_bounds__(256) void k_ln1024_red(
        const float* __restrict__ p0, const float* __restrict__ p1,
        const float* __restrict__ bias, const float* __restrict__ g,
        const float* __restrict__ b, float* __restrict__ out) {
    __shared__ float red[4];
    int row = blockIdx.x, tid = threadIdx.x;
    const float4 v0 = *(const float4*)(p0 + (size_t)row * 1024 + tid * 4);
    const float4 v1 = *(const float4*)(p1 + (size_t)row * 1024 + tid * 4);
    const float4 bb = *(const float4*)(bias + tid * 4);
    float4 v;
    v.x = v0.x + v1.x + bb.x;
    v.y = v0.y + v1.y + bb.y;
    v.z = v0.z + v1.z + bb.z;
    v.w = v0.w + v1.w + bb.w;
    float s = v.x + v.y + v.z + v.w;
#pragma unroll
    for (int off = 32; off; off >>= 1) s += __shfl_xor(s, off);
    if ((tid & 63) == 0) red[tid >> 6] = s;
    __syncthreads();
    float mu = (red[0] + red[1] + red[2] + red[3]) * (1.0f / 1024.0f);
    float dx = v.x - mu, dy = v.y - mu, dz = v.z - mu, dw = v.w - mu;
    float q = dx * dx + dy * dy + dz * dz + dw * dw;
#pragma unroll
    for (int off = 32; off; off >>= 1) q += __shfl_xor(q, off);
    __syncthreads();
    if ((tid & 63) == 0) red[tid >> 6] = q;
    __syncthreads();
    float rs = rsqrtf((red[0] + red[1] + red[2] + red[3]) * (1.0f / 1024.0f) + 1e-9f);
    const float4 gv = *(const float4*)(g + tid * 4);
    const float4 bv = *(const float4*)(b + tid * 4);
    float4 o;
    o.x = dx * rs * gv.x + bv.x;
    o.y = dy * rs * gv.y + bv.y;
    o.z = dz * rs * gv.z + bv.z;
    o.w = dw * rs * gv.w + bv.w;
    *(float4*)(out + (size_t)row * 1024 + tid * 4) = o;
}

__global__ void k_finalize(const float* __restrict__ accum, float* __restrict__ out) {
    // km_i = accum_i / 4096^2 ; reg = (km0 + km1 - 2*km2) / B * S = mmd * 64
    out[0] = (accum[0] + accum[8] - 2.0f * accum[16]) * (64.0f / (4096.0f * 4096.0f));
}

// ---------------------------------------------------------------------------
extern "C" void kernel_launch(void* const* d_in, const int* in_sizes, int n_in,
                              void* d_out, int out_size, void* d_ws, size_t ws_size,
                              hipStream_t stream) {
    const float* hidden   = (const float*)d_in[0];
    const float* tsamp    = (const float*)d_in[1];
    const float* enc_w1   = (const float*)d_in[2];
    const float* enc_b1   = (const float*)d_in[3];
    const float* enc_w2   = (const float*)d_in[4];
    const float* enc_b2   = (const float*)d_in[5];
    const float* enc_ln_g = (const float*)d_in[6];
    const float* enc_ln_b = (const float*)d_in[7];
    const float* dec_w1   = (const float*)d_in[8];
    const float* dec_b1   = (const float*)d_in[9];
    const float* dec_w2   = (const float*)d_in[10];
    const float* dec_b2   = (const float*)d_in[11];
    const float* dec_ln_g = (const float*)d_in[12];
    const float* dec_ln_b = (const float*)d_in[13];

    float* out      = (float*)d_out;
    float* recon    = out;                 // 4096*1024
    float* latent_f = out + 4194304;       // 4096*64
    float* reg      = out + 4456448;       // scalar

    char* ws = (char*)d_ws;
    const size_t MB = 1024 * 1024;
    ushort* A1bf = (ushort*)(ws + 0);                 // 8MB  hidden bf16 (dead after GEMM1)
    ushort* W1t  = (ushort*)(ws + 8 * MB);            // 8MB  (dead after GEMM1)
    float*  part = (float*)(ws + 0);                  // 16MB GEMM2 split-K partials [16][4096,64]
    float*  h4p0 = (float*)(ws + 0);                  // 16MB GEMM4 partial z=0 (z=1 -> recon buf)
    ushort* H1bf = (ushort*)(ws + 16 * MB);           // 32MB enc hidden, later dec hidden
    ushort* W4t  = (ushort*)(ws + 48 * MB);           // 8MB  [1024,4096]
    ushort* W2t  = (ushort*)(ws + 56 * MB);           // 512K [64,4096]
    ushort* W3t  = (ushort*)(ws + 56 * MB + 512 * 1024); // 512K [4096,64]
    ushort* Lbf  = (ushort*)(ws + 57 * MB);           // 512K latent bf16
    float*  sq_t = (float*)(ws + 59 * MB);            // 16KB
    float*  sq_l = (float*)(ws + 59 * MB + 16384);    // 16KB
    float*  acc3 = (float*)(ws + 59 * MB + 32768);    // 3 accumulators @ 64B stride
    ushort* Tbf  = (ushort*)(ws + 59 * MB + 65536);   // 512K tsamp bf16

    // pre-pass: all conversions, transposes, tsamp sqnorms, accumulator zeroing
    k_pre<<<13056, 256, 0, stream>>>(hidden, A1bf, tsamp, Tbf, sq_t, acc3,
                                     enc_w1, W1t, enc_w2, W2t,
                                     dec_w1, W3t, dec_w2, W4t);

    // encoder
    k_gemm<64, 0, false><<<dim3(64, 32, 1), 256, 0, stream>>>(
        A1bf, W1t, enc_b1, H1bf, nullptr, 4096, 4096, 1024, 1024);
    // GEMM2 split-K=16: 512 blocks = 2/CU
    k_gemm<64, 2, false><<<dim3(1, 32, 16), 256, 0, stream>>>(
        H1bf, W2t, nullptr, part, nullptr, 4096, 64, 4096, 256);
    k_ln64_red<<<1024, 256, 0, stream>>>(part, 16, enc_b2, enc_ln_g, enc_ln_b,
                                         latent_f, Lbf, sq_l);

    // decoder
    k_gemm<64, 0, false><<<dim3(64, 32, 1), 256, 0, stream>>>(
        Lbf, W3t, dec_b1, H1bf, nullptr, 4096, 4096, 64, 64);
    // GEMM4 split-K=2 + m-fast swizzle (proven 51.3us; de-split was 61us)
    k_gemm<64, 2, true><<<dim3(16, 32, 2), 256, 0, stream>>>(
        H1bf, W4t, nullptr, h4p0, recon, 4096, 1024, 4096, 2048);
    k_ln1024_red<<<4096, 256, 0, stream>>>(h4p0, recon, dec_b2, dec_ln_g,
                                           dec_ln_b, recon);

    // MMD: grams (separate-line accumulators), then tiny finalize
    k_gram_all<<<2080, 256, 0, stream>>>(Tbf, Lbf, sq_t, sq_l, acc3);
    k_finalize<<<1, 1, 0, stream>>>(acc3, reg);
}